// Round 1
// baseline (3096.962 us; speedup 1.0000x reference)
//
#include <hip/hip_runtime.h>
#include <math.h>

#define T_ 512
#define B_ 64
#define V_ 50000
#define E_ 300
#define H_ 256
#define K_ 20
#define G4 1024  /* 4*H */

typedef _Float16 h2_t __attribute__((ext_vector_type(2)));

union U32H2 { unsigned u; h2_t h; };

__device__ __forceinline__ h2_t u2h(unsigned u) { U32H2 x; x.u = u; return x.h; }
__device__ __forceinline__ unsigned h2u(h2_t h) { U32H2 x; x.h = h; return x.u; }

__device__ __forceinline__ float fdot2f(h2_t a, h2_t b, float c) {
#if __has_builtin(__builtin_amdgcn_fdot2)
  return __builtin_amdgcn_fdot2(a, b, c, false);
#else
  return c + (float)a.x * (float)b.x + (float)a.y * (float)b.y;
#endif
}

__device__ __forceinline__ float sigf(float x) { return 1.f / (1.f + __expf(-x)); }
__device__ __forceinline__ float tanhfast(float x) { return 1.f - 2.f / (__expf(2.f * x) + 1.f); }

// ---------------- prep: transpose w_ih, pack w_hh to half2 pairs, combine biases, zero out ----
__global__ void prep_kernel(const float* __restrict__ w_ih, const float* __restrict__ w_hh,
                            const float* __restrict__ b_ih, const float* __restrict__ b_hh,
                            float* __restrict__ w_ihT, unsigned* __restrict__ wh2,
                            float* __restrict__ b_comb, float* __restrict__ out) {
  int tid = blockIdx.x * blockDim.x + threadIdx.x;
  int nth = gridDim.x * blockDim.x;
  // w_ihT[e][row] = w_ih[row][e]
  for (int i = tid; i < E_ * G4; i += nth) {
    int e = i >> 10, row = i & 1023;
    w_ihT[i] = w_ih[row * E_ + e];
  }
  // wh2[k2][row] = half2(w_hh[row][2k2], w_hh[row][2k2+1])
  for (int i = tid; i < 128 * G4; i += nth) {
    int k2 = i >> 10, row = i & 1023;
    h2_t h;
    h.x = (_Float16)w_hh[row * H_ + 2 * k2];
    h.y = (_Float16)w_hh[row * H_ + 2 * k2 + 1];
    wh2[i] = h2u(h);
  }
  for (int i = tid; i < G4; i += nth) b_comb[i] = b_ih[i] + b_hh[i];
  if (tid == 0) out[0] = 0.f;
}

// ---------------- kernel A: g_in[t][b][row] (f16) = emb[inp[t,b]] @ w_ih^T + b_ih + b_hh ------
__global__ __launch_bounds__(256) void kernelA(const int* __restrict__ inp,
                                               const float* __restrict__ emb,
                                               const float* __restrict__ w_ihT,
                                               const float* __restrict__ b_comb,
                                               unsigned* __restrict__ g_in_u) {
  __shared__ float xs[32][304];
  __shared__ int ridx[32];
  int bm = blockIdx.x >> 2;   // 1024 row-tiles of 32 rows (T*B = 32768)
  int bn = blockIdx.x & 3;    // 4 col-tiles of 256 cols
  int tid = threadIdx.x;
  if (tid < 32) ridx[tid] = inp[bm * 32 + tid];
  __syncthreads();
  // gather 32 embedding rows (300 floats = 75 float4 each)
  for (int i = tid; i < 32 * 75; i += 256) {
    int r = i / 75, c = i % 75;
    float4 v = *(const float4*)(emb + (long)ridx[r] * E_ + c * 4);
    *(float4*)&xs[r][c * 4] = v;
  }
  __syncthreads();
  int cx = tid & 63, ry = tid >> 6;
  int col = bn * 256 + cx * 4;
  float4 acc[8];
#pragma unroll
  for (int r = 0; r < 8; r++) acc[r] = make_float4(0.f, 0.f, 0.f, 0.f);
#pragma unroll 4
  for (int e = 0; e < E_; e++) {
    float4 w = *(const float4*)(w_ihT + e * G4 + col);
#pragma unroll
    for (int r = 0; r < 8; r++) {
      float xv = xs[ry * 8 + r][e];
      acc[r].x += xv * w.x; acc[r].y += xv * w.y;
      acc[r].z += xv * w.z; acc[r].w += xv * w.w;
    }
  }
  float4 bb = *(const float4*)(b_comb + col);
#pragma unroll
  for (int r = 0; r < 8; r++) {
    float4 o = acc[r];
    o.x += bb.x; o.y += bb.y; o.z += bb.z; o.w += bb.w;
    h2_t p0, p1;
    p0.x = (_Float16)o.x; p0.y = (_Float16)o.y;
    p1.x = (_Float16)o.z; p1.y = (_Float16)o.w;
    uint2 st; st.x = h2u(p0); st.y = h2u(p1);
    long row = (long)bm * 32 + ry * 8 + r;
    *(uint2*)(g_in_u + ((row * G4 + col) >> 1)) = st;
  }
}

// ---------------- kernel B: sequential LSTM, one block per batch element ---------------------
__global__ __launch_bounds__(256) void kernelB(const unsigned* __restrict__ g_in_u,
                                               const unsigned* __restrict__ wh2,
                                               float* __restrict__ houts) {
  int b = blockIdx.x;
  int j = threadIdx.x;  // handles gate rows 4j..4j+3
  __shared__ float gbuf[1024];
  __shared__ unsigned h2buf[2][128];
  if (j < 128) { h2buf[0][j] = 0u; h2buf[1][j] = 0u; }
  float c0 = 0.f, c1 = 0.f;
  int p = 0;
  __syncthreads();
  const unsigned* wbase = wh2 + 4 * j;
  for (int t = 0; t < T_; t++) {
    // input gates (precomputed), issued early to overlap with the matvec
    uint2 gv = *(const uint2*)(g_in_u + ((((long)t * B_ + b) * G4 + 4 * j) >> 1));
    float a0 = 0.f, a1 = 0.f, a2 = 0.f, a3 = 0.f;
#pragma unroll 8
    for (int k2 = 0; k2 < 128; k2++) {
      h2_t hh = u2h(h2buf[p][k2]);
      uint4 w = *(const uint4*)(wbase + k2 * G4);
      a0 = fdot2f(u2h(w.x), hh, a0);
      a1 = fdot2f(u2h(w.y), hh, a1);
      a2 = fdot2f(u2h(w.z), hh, a2);
      a3 = fdot2f(u2h(w.w), hh, a3);
    }
    h2_t g0 = u2h(gv.x), g1 = u2h(gv.y);
    gbuf[4 * j + 0] = a0 + (float)g0.x;
    gbuf[4 * j + 1] = a1 + (float)g0.y;
    gbuf[4 * j + 2] = a2 + (float)g1.x;
    gbuf[4 * j + 3] = a3 + (float)g1.y;
    __syncthreads();
    if (j < 128) {
      // hidden units 2j, 2j+1 ; gate order i,f,g,o
      float gi0 = gbuf[2 * j], gi1 = gbuf[2 * j + 1];
      float gf0 = gbuf[256 + 2 * j], gf1 = gbuf[256 + 2 * j + 1];
      float gg0 = gbuf[512 + 2 * j], gg1 = gbuf[512 + 2 * j + 1];
      float go0 = gbuf[768 + 2 * j], go1 = gbuf[768 + 2 * j + 1];
      c0 = sigf(gf0) * c0 + sigf(gi0) * tanhfast(gg0);
      c1 = sigf(gf1) * c1 + sigf(gi1) * tanhfast(gg1);
      float h0 = sigf(go0) * tanhfast(c0);
      float h1 = sigf(go1) * tanhfast(c1);
      h2_t hp; hp.x = (_Float16)h0; hp.y = (_Float16)h1;
      h2buf[1 - p][j] = h2u(hp);
      *(float2*)(houts + ((long)t * B_ + b) * H_ + 2 * j) = make_float2(h0, h1);
    }
    p ^= 1;
    __syncthreads();
  }
}

// ---------------- kernel C: emissions = houts @ W_lin^T + b_lin ------------------------------
__global__ __launch_bounds__(256) void kernelC(const float* __restrict__ houts,
                                               const float* __restrict__ W_lin,
                                               const float* __restrict__ b_lin,
                                               float* __restrict__ em) {
  __shared__ float hs[32][260];
  __shared__ float wl[20][260];
  __shared__ float bl[20];
  int bm = blockIdx.x;  // 1024 blocks x 32 rows
  int tid = threadIdx.x;
  for (int i = tid; i < 32 * 64; i += 256) {
    int r = i >> 6, c = i & 63;
    *(float4*)&hs[r][c * 4] = *(const float4*)(houts + ((long)bm * 32 + r) * H_ + c * 4);
  }
  for (int i = tid; i < 20 * 64; i += 256) {
    int k = i >> 6, c = i & 63;
    *(float4*)&wl[k][c * 4] = *(const float4*)(W_lin + k * H_ + c * 4);
  }
  if (tid < 20) bl[tid] = b_lin[tid];
  __syncthreads();
  for (int o = tid; o < 32 * 20; o += 256) {
    int r = o / 20, k = o % 20;
    float s = 0.f;
#pragma unroll 4
    for (int i = 0; i < H_; i++) s += hs[r][i] * wl[k][i];
    em[(long)bm * 32 * K_ + o] = s + bl[k];
  }
}

// ---------------- kernel D: CRF forward DP + gold score + NLL reduction ----------------------
__global__ __launch_bounds__(64) void kernelD(const float* __restrict__ em,
                                              const int* __restrict__ labels,
                                              const float* __restrict__ start_t,
                                              const float* __restrict__ end_t,
                                              const float* __restrict__ trans,
                                              float* __restrict__ out) {
  int b = blockIdx.x;
  int k = threadIdx.x;
  __shared__ float tr[400];
  __shared__ float alpha[2][20];
  for (int i = k; i < 400; i += 64) tr[i] = trans[i];
  float score = 0.f;
  int prevtag = 0;
  if (k == 0) {
    int t0 = labels[b];
    score = start_t[t0] + em[b * K_ + t0];
    prevtag = t0;
  }
  if (k < K_) alpha[0][k] = start_t[k] + em[b * K_ + k];
  __syncthreads();
  int p = 0;
  for (int t = 1; t < T_; t++) {
    const float* emrow = em + ((long)t * B_ + b) * K_;
    if (k < K_) {
      float v[20];
      float m = -1e30f;
#pragma unroll
      for (int j = 0; j < 20; j++) {
        v[j] = alpha[p][j] + tr[j * 20 + k];
        m = fmaxf(m, v[j]);
      }
      float s = 0.f;
#pragma unroll
      for (int j = 0; j < 20; j++) s += __expf(v[j] - m);
      alpha[1 - p][k] = emrow[k] + m + __logf(s);
    }
    if (k == 0) {
      int tg = labels[t * B_ + b];
      score += tr[prevtag * 20 + tg] + emrow[tg];
      prevtag = tg;
    }
    p ^= 1;
    __syncthreads();
  }
  if (k == 0) {
    score += end_t[prevtag];
    float m = -1e30f;
    for (int j = 0; j < 20; j++) m = fmaxf(m, alpha[p][j] + end_t[j]);
    float s = 0.f;
    for (int j = 0; j < 20; j++) s += __expf(alpha[p][j] + end_t[j] - m);
    float logZ = m + __logf(s);
    atomicAdd(out, -(score - logZ));
  }
}

extern "C" void kernel_launch(void* const* d_in, const int* in_sizes, int n_in,
                              void* d_out, int out_size, void* d_ws, size_t ws_size,
                              hipStream_t stream) {
  const int*   inp     = (const int*)d_in[0];
  const int*   labels  = (const int*)d_in[1];
  const float* emb     = (const float*)d_in[2];
  const float* w_ih    = (const float*)d_in[3];
  const float* w_hh    = (const float*)d_in[4];
  const float* b_ih    = (const float*)d_in[5];
  const float* b_hh    = (const float*)d_in[6];
  const float* W_lin   = (const float*)d_in[7];
  const float* b_lin   = (const float*)d_in[8];
  const float* start_t = (const float*)d_in[9];
  const float* end_t   = (const float*)d_in[10];
  const float* trans   = (const float*)d_in[11];
  float* out = (float*)d_out;
  char* ws = (char*)d_ws;

  // ws layout (bytes):
  unsigned* g_in_u = (unsigned*)(ws);                          // 67,108,864  (T*B*1024 f16)
  float*    houts  = (float*)(ws + 67108864);                  // 33,554,432  (T*B*H f32)
  float*    em     = (float*)(ws + 100663296);                 //  2,621,440  (T*B*K f32)
  float*    w_ihT  = (float*)(ws + 103284736);                 //  1,228,800  (300x1024 f32)
  unsigned* wh2    = (unsigned*)(ws + 104513536);              //    524,288  (128x1024 half2)
  float*    b_comb = (float*)(ws + 105037824);                 //      4,096
  // total ~105 MB

  prep_kernel<<<512, 256, 0, stream>>>(w_ih, w_hh, b_ih, b_hh, w_ihT, wh2, b_comb, out);
  kernelA<<<4096, 256, 0, stream>>>(inp, emb, w_ihT, b_comb, g_in_u);
  kernelB<<<64, 256, 0, stream>>>(g_in_u, wh2, houts);
  kernelC<<<1024, 256, 0, stream>>>(houts, W_lin, b_lin, em);
  kernelD<<<64, 64, 0, stream>>>(em, labels, start_t, end_t, trans, out);
}

// Round 2
// 1761.052 us; speedup vs baseline: 1.7586x; 1.7586x over previous
//
#include <hip/hip_runtime.h>
#include <math.h>

#define T_ 512
#define B_ 64
#define V_ 50000
#define E_ 300
#define H_ 256
#define K_ 20
#define G4 1024  /* 4*H */

typedef float f4 __attribute__((ext_vector_type(4)));

__device__ __forceinline__ float sigf(float x) { return 1.f / (1.f + __expf(-x)); }
__device__ __forceinline__ float tanhfast(float x) { return 1.f - 2.f / (__expf(2.f * x) + 1.f); }

__device__ __forceinline__ unsigned char f32_e4m3(float x) {
  return (unsigned char)(__builtin_amdgcn_cvt_pk_fp8_f32(x, x, 0, false) & 0xff);
}

// ---------------- prep: transpose w_ih, quantize w_hh to fp8 e4m3 (x64), biases, zero out ----
__global__ void prep_kernel(const float* __restrict__ w_ih, const float* __restrict__ w_hh,
                            const float* __restrict__ b_ih, const float* __restrict__ b_hh,
                            float* __restrict__ w_ihT, unsigned char* __restrict__ W8,
                            float* __restrict__ b_comb, float* __restrict__ out) {
  int tid = blockIdx.x * blockDim.x + threadIdx.x;
  int nth = gridDim.x * blockDim.x;
  for (int i = tid; i < E_ * G4; i += nth) {
    int e = i >> 10, row = i & 1023;
    w_ihT[i] = w_ih[row * E_ + e];
  }
  // W8[row][k] = e4m3(w_hh[row][k] * 64)
  for (int i = tid; i < G4 * H_; i += nth) {
    W8[i] = f32_e4m3(w_hh[i] * 64.f);
  }
  for (int i = tid; i < G4; i += nth) b_comb[i] = b_ih[i] + b_hh[i];
  if (tid == 0) out[0] = 0.f;
}

// ---------------- kernel A: g_in[t][b][row] (f16) = emb[inp[t,b]] @ w_ih^T + b_ih + b_hh ------
typedef _Float16 h2_t __attribute__((ext_vector_type(2)));
union U32H2 { unsigned u; h2_t h; };
__device__ __forceinline__ unsigned h2u(h2_t h) { U32H2 x; x.h = h; return x.u; }

__global__ __launch_bounds__(256) void kernelA(const int* __restrict__ inp,
                                               const float* __restrict__ emb,
                                               const float* __restrict__ w_ihT,
                                               const float* __restrict__ b_comb,
                                               unsigned* __restrict__ g_in_u) {
  __shared__ float xs[32][304];
  __shared__ int ridx[32];
  int bm = blockIdx.x >> 2;   // 1024 row-tiles of 32 rows (T*B = 32768)
  int bn = blockIdx.x & 3;    // 4 col-tiles of 256 cols
  int tid = threadIdx.x;
  if (tid < 32) ridx[tid] = inp[bm * 32 + tid];
  __syncthreads();
  for (int i = tid; i < 32 * 75; i += 256) {
    int r = i / 75, c = i % 75;
    float4 v = *(const float4*)(emb + (long)ridx[r] * E_ + c * 4);
    *(float4*)&xs[r][c * 4] = v;
  }
  __syncthreads();
  int cx = tid & 63, ry = tid >> 6;
  int col = bn * 256 + cx * 4;
  float4 acc[8];
#pragma unroll
  for (int r = 0; r < 8; r++) acc[r] = make_float4(0.f, 0.f, 0.f, 0.f);
#pragma unroll 4
  for (int e = 0; e < E_; e++) {
    float4 w = *(const float4*)(w_ihT + e * G4 + col);
#pragma unroll
    for (int r = 0; r < 8; r++) {
      float xv = xs[ry * 8 + r][e];
      acc[r].x += xv * w.x; acc[r].y += xv * w.y;
      acc[r].z += xv * w.z; acc[r].w += xv * w.w;
    }
  }
  float4 bb = *(const float4*)(b_comb + col);
#pragma unroll
  for (int r = 0; r < 8; r++) {
    float4 o = acc[r];
    o.x += bb.x; o.y += bb.y; o.z += bb.z; o.w += bb.w;
    h2_t p0, p1;
    p0.x = (_Float16)o.x; p0.y = (_Float16)o.y;
    p1.x = (_Float16)o.z; p1.y = (_Float16)o.w;
    uint2 st; st.x = h2u(p0); st.y = h2u(p1);
    long row = (long)bm * 32 + ry * 8 + r;
    *(uint2*)(g_in_u + ((row * G4 + col) >> 1)) = st;
  }
}

// ---------------- kernel B: sequential LSTM, fp8 MFMA, weights register-resident -------------
// 16 blocks; block bb handles batches 4bb..4bb+3. 1024 threads = 16 waves, <=128 VGPRs.
// Wave w owns row-tiles {w, w+16, w+32, w+48} = gates i,f,g,o for units 16w..16w+15.
#define WSCALE 64.f
#define HSCALE 16.f
#define DESCALE (1.f / (WSCALE * HSCALE))

__global__ __launch_bounds__(1024, 4) void kernelB(const _Float16* __restrict__ g_in,
                                                   const unsigned char* __restrict__ W8,
                                                   float* __restrict__ houts) {
  int bb = blockIdx.x;
  int tid = threadIdx.x;
  int lane = tid & 63, w = tid >> 6;
  int col = lane & 15, quad = lane >> 4;

  __shared__ unsigned char h8[16 * 272];        // [col(batch)][k-permuted], pad 272
  __shared__ float glds[4 * 4 * 264];           // [gate][batch][unit], pad 264

  for (int i = tid; i < 16 * 272; i += 1024) h8[i] = 0;

  // Load persistent A-fragments: wf[tau][c] = 8 fp8 of W[16*(w+16*tau)+col][32c + quad*8 .. +7]
  unsigned long long wf[4][8];
#pragma unroll
  for (int tau = 0; tau < 4; tau++) {
    const unsigned char* rp = W8 + (unsigned)(16 * (w + 16 * tau) + col) * 256 + quad * 8;
#pragma unroll
    for (int c = 0; c < 8; c++)
      wf[tau][c] = *(const unsigned long long*)(rp + 32 * c);
  }

  // h-compute identity: thread = hb*256 + hu
  int hb = tid >> 8;    // 0..3 local batch
  int hu = tid & 255;   // hidden unit
  float cst = 0.f;
  const unsigned char* bptr = &h8[col * 272 + quad * 64];
  // h8 write slot for h-compute: k = hu -> [q][c][j] with q=(hu>>3)&3, c=hu>>5, j=hu&7
  int h8slot = hb * 272 + ((hu >> 3) & 3) * 64 + (hu >> 5) * 8 + (hu & 7);
  const _Float16* gbase = g_in + ((long)(4 * bb + hb)) * G4 + hu;

  __syncthreads();

  for (int t = 0; t < T_; t++) {
    // prefetch input-gate contributions (independent of h8)
    const _Float16* gp = gbase + (long)t * B_ * G4;
    float giv = (float)gp[0];
    float gfv = (float)gp[256];
    float ggv = (float)gp[512];
    float gov = (float)gp[768];

    f4 acc0 = {0.f, 0.f, 0.f, 0.f}, acc1 = acc0, acc2 = acc0, acc3 = acc0;
#pragma unroll
    for (int i = 0; i < 4; i++) {
      ulonglong2 bv = *(const ulonglong2*)(bptr + i * 16);
      long long b0 = (long long)bv.x;   // chunk 2i
      long long b1 = (long long)bv.y;   // chunk 2i+1
      acc0 = __builtin_amdgcn_mfma_f32_16x16x32_fp8_fp8((long long)wf[0][2 * i], b0, acc0, 0, 0, 0);
      acc1 = __builtin_amdgcn_mfma_f32_16x16x32_fp8_fp8((long long)wf[1][2 * i], b0, acc1, 0, 0, 0);
      acc2 = __builtin_amdgcn_mfma_f32_16x16x32_fp8_fp8((long long)wf[2][2 * i], b0, acc2, 0, 0, 0);
      acc3 = __builtin_amdgcn_mfma_f32_16x16x32_fp8_fp8((long long)wf[3][2 * i], b0, acc3, 0, 0, 0);
      acc0 = __builtin_amdgcn_mfma_f32_16x16x32_fp8_fp8((long long)wf[0][2 * i + 1], b1, acc0, 0, 0, 0);
      acc1 = __builtin_amdgcn_mfma_f32_16x16x32_fp8_fp8((long long)wf[1][2 * i + 1], b1, acc1, 0, 0, 0);
      acc2 = __builtin_amdgcn_mfma_f32_16x16x32_fp8_fp8((long long)wf[2][2 * i + 1], b1, acc2, 0, 0, 0);
      acc3 = __builtin_amdgcn_mfma_f32_16x16x32_fp8_fp8((long long)wf[3][2 * i + 1], b1, acc3, 0, 0, 0);
    }
    // stage gates: D layout col=lane&15 (batch), row(unit-in-tile) = quad*4 + reg
    if (col < 4) {
      int u0 = 16 * w + quad * 4;
      *(f4*)&glds[(0 * 4 + col) * 264 + u0] = acc0;
      *(f4*)&glds[(1 * 4 + col) * 264 + u0] = acc1;
      *(f4*)&glds[(2 * 4 + col) * 264 + u0] = acc2;
      *(f4*)&glds[(3 * 4 + col) * 264 + u0] = acc3;
    }
    __syncthreads();
    // elementwise: one (batch, unit) per thread
    {
      float gi = glds[(0 * 4 + hb) * 264 + hu] * DESCALE + giv;
      float gf = glds[(1 * 4 + hb) * 264 + hu] * DESCALE + gfv;
      float gg = glds[(2 * 4 + hb) * 264 + hu] * DESCALE + ggv;
      float go = glds[(3 * 4 + hb) * 264 + hu] * DESCALE + gov;
      cst = sigf(gf) * cst + sigf(gi) * tanhfast(gg);
      float h = sigf(go) * tanhfast(cst);
      houts[((long)t * B_ + 4 * bb + hb) * H_ + hu] = h;
      h8[h8slot] = f32_e4m3(h * HSCALE);
    }
    __syncthreads();
  }
}

// ---------------- kernel C: emissions = houts @ W_lin^T + b_lin ------------------------------
__global__ __launch_bounds__(256) void kernelC(const float* __restrict__ houts,
                                               const float* __restrict__ W_lin,
                                               const float* __restrict__ b_lin,
                                               float* __restrict__ em) {
  __shared__ float hs[32][260];
  __shared__ float wl[20][260];
  __shared__ float bl[20];
  int bm = blockIdx.x;
  int tid = threadIdx.x;
  for (int i = tid; i < 32 * 64; i += 256) {
    int r = i >> 6, c = i & 63;
    *(float4*)&hs[r][c * 4] = *(const float4*)(houts + ((long)bm * 32 + r) * H_ + c * 4);
  }
  for (int i = tid; i < 20 * 64; i += 256) {
    int k = i >> 6, c = i & 63;
    *(float4*)&wl[k][c * 4] = *(const float4*)(W_lin + k * H_ + c * 4);
  }
  if (tid < 20) bl[tid] = b_lin[tid];
  __syncthreads();
  for (int o = tid; o < 32 * 20; o += 256) {
    int r = o / 20, k = o % 20;
    float s = 0.f;
#pragma unroll 4
    for (int i = 0; i < H_; i++) s += hs[r][i] * wl[k][i];
    em[(long)bm * 32 * K_ + o] = s + bl[k];
  }
}

// ---------------- kernel D: CRF forward DP + gold score + NLL reduction ----------------------
__global__ __launch_bounds__(64) void kernelD(const float* __restrict__ em,
                                              const int* __restrict__ labels,
                                              const float* __restrict__ start_t,
                                              const float* __restrict__ end_t,
                                              const float* __restrict__ trans,
                                              float* __restrict__ out) {
  int b = blockIdx.x;
  int k = threadIdx.x;
  __shared__ float tr[400];
  __shared__ float alpha[2][20];
  for (int i = k; i < 400; i += 64) tr[i] = trans[i];
  float score = 0.f;
  int prevtag = 0;
  if (k == 0) {
    int t0 = labels[b];
    score = start_t[t0] + em[b * K_ + t0];
    prevtag = t0;
  }
  if (k < K_) alpha[0][k] = start_t[k] + em[b * K_ + k];
  __syncthreads();
  int p = 0;
  for (int t = 1; t < T_; t++) {
    const float* emrow = em + ((long)t * B_ + b) * K_;
    if (k < K_) {
      float v[20];
      float m = -1e30f;
#pragma unroll
      for (int j = 0; j < 20; j++) {
        v[j] = alpha[p][j] + tr[j * 20 + k];
        m = fmaxf(m, v[j]);
      }
      float s = 0.f;
#pragma unroll
      for (int j = 0; j < 20; j++) s += __expf(v[j] - m);
      alpha[1 - p][k] = emrow[k] + m + __logf(s);
    }
    if (k == 0) {
      int tg = labels[t * B_ + b];
      score += tr[prevtag * 20 + tg] + emrow[tg];
      prevtag = tg;
    }
    p ^= 1;
    __syncthreads();
  }
  if (k == 0) {
    score += end_t[prevtag];
    float m = -1e30f;
    for (int j = 0; j < 20; j++) m = fmaxf(m, alpha[p][j] + end_t[j]);
    float s = 0.f;
    for (int j = 0; j < 20; j++) s += __expf(alpha[p][j] + end_t[j] - m);
    float logZ = m + __logf(s);
    atomicAdd(out, -(score - logZ));
  }
}

extern "C" void kernel_launch(void* const* d_in, const int* in_sizes, int n_in,
                              void* d_out, int out_size, void* d_ws, size_t ws_size,
                              hipStream_t stream) {
  const int*   inp     = (const int*)d_in[0];
  const int*   labels  = (const int*)d_in[1];
  const float* emb     = (const float*)d_in[2];
  const float* w_ih    = (const float*)d_in[3];
  const float* w_hh    = (const float*)d_in[4];
  const float* b_ih    = (const float*)d_in[5];
  const float* b_hh    = (const float*)d_in[6];
  const float* W_lin   = (const float*)d_in[7];
  const float* b_lin   = (const float*)d_in[8];
  const float* start_t = (const float*)d_in[9];
  const float* end_t   = (const float*)d_in[10];
  const float* trans   = (const float*)d_in[11];
  float* out = (float*)d_out;
  char* ws = (char*)d_ws;

  // ws layout (bytes):
  unsigned*      g_in_u = (unsigned*)(ws);                     // 67,108,864  (T*B*1024 f16)
  float*         houts  = (float*)(ws + 67108864);             // 33,554,432  (T*B*H f32)
  float*         em     = (float*)(ws + 100663296);            //  2,621,440  (T*B*K f32)
  float*         w_ihT  = (float*)(ws + 103284736);            //  1,228,800  (300x1024 f32)
  unsigned char* W8     = (unsigned char*)(ws + 104513536);    //    262,144  (1024x256 fp8)
  float*         b_comb = (float*)(ws + 104775680);            //      4,096
  // total ~104.8 MB

  prep_kernel<<<512, 256, 0, stream>>>(w_ih, w_hh, b_ih, b_hh, w_ihT, W8, b_comb, out);
  kernelA<<<4096, 256, 0, stream>>>(inp, emb, w_ihT, b_comb, g_in_u);
  kernelB<<<16, 1024, 0, stream>>>((const _Float16*)g_in_u, W8, houts);
  kernelC<<<1024, 256, 0, stream>>>(houts, W_lin, b_lin, em);
  kernelD<<<64, 64, 0, stream>>>(em, labels, start_t, end_t, trans, out);
}